// Round 2
// baseline (286.137 us; speedup 1.0000x reference)
//
#include <hip/hip_runtime.h>

// ---------- problem constants ----------
#define B_      16
#define C_IN    3
#define IMG     512
#define PATCH   16
#define C_FEAT  2048
#define N_CLS   18
#define KCELL   24
#define HF      32
#define P_      (HF*HF)        // 1024
#define KDIM    (C_IN*PATCH*PATCH) // 768
#define M_GEMM1 (B_*P_)        // 16384
#define EPS_    1e-6f

typedef __attribute__((ext_vector_type(8))) short bf16x8;
typedef __attribute__((ext_vector_type(4))) float f32x4;
typedef __attribute__((ext_vector_type(4))) unsigned short us4;
typedef __attribute__((ext_vector_type(4))) float fl4;

#define DEVFN static __device__ __forceinline__

DEVFN unsigned short f2bf(float f) {  // RNE f32->bf16
  union { float f; unsigned u; } x; x.f = f;
  unsigned r = (x.u + 0x7fffu + ((x.u >> 16) & 1u)) >> 16;
  return (unsigned short)r;
}
DEVFN float bf2f(unsigned short u) {
  union { unsigned u; float f; } x; x.u = ((unsigned)u) << 16;
  return x.f;
}
DEVFN f32x4 mfma16(bf16x8 a, bf16x8 b, f32x4 c) {
  return __builtin_amdgcn_mfma_f32_16x16x32_bf16(a, b, c, 0, 0, 0);
}
#define GLOAD16(gp, lp) __builtin_amdgcn_global_load_lds( \
    (const __attribute__((address_space(1))) unsigned int*)(gp), \
    (__attribute__((address_space(3))) unsigned int*)(lp), 16, 0, 0)

// ---------- ws layout (bytes) ----------
#define OFF_A     0u            // A_bf16 [16384][768]        25,165,824
#define OFF_WB    25165824u     // Wb_bf16 [2048][768]         3,145,728
#define OFF_W1    28311552u     // W1_bf16 [1024][2048]        4,194,304
#define OFF_W2    32505856u     // W2_bf16 [18][1024]             36,864
#define OFF_FM    32542720u     // fm_bf16 [16384][2048]      67,108,864
#define OFF_MB    99651584u     // masks_bf16 [16][32][1024]   1,048,576
#define OFF_AREA  100700160u    // area [16*32] f32                2,048
#define OFF_CF    100702208u    // CF_bf16 [384][2048]         1,572,864
#define OFF_CL    102275072u    // cl f32 [384][18]               27,648
#define OFF_H     102302720u    // h_bf16 [384][1024]            786,432
#define WS_NEED   103089152u

// ---------- fp32 -> bf16 convert (weights) ----------
__global__ __launch_bounds__(256) void k_f2bf(const float* __restrict__ s,
                                              unsigned short* __restrict__ d, int n4) {
  int i = blockIdx.x * 256 + threadIdx.x;
  if (i >= n4) return;
  fl4 v = *(const fl4*)(s + (size_t)i * 4);
  us4 o;
  o[0] = f2bf(v[0]); o[1] = f2bf(v[1]); o[2] = f2bf(v[2]); o[3] = f2bf(v[3]);
  *(us4*)(d + (size_t)i * 4) = o;
}

// ---------- masks: fp32 -> bf16, pad rows 24..31 with zeros, compute area ----------
__global__ __launch_bounds__(256) void k_prep_masks(const float* __restrict__ masks,
                                                    unsigned short* __restrict__ mb,
                                                    float* __restrict__ area) {
  int bm = blockIdx.x;           // 0..511
  int b = bm >> 5, m = bm & 31;
  int t = threadIdx.x;
  unsigned short* dst = mb + ((size_t)(b * 32 + m)) * P_;
  float s = 0.f;
  if (m < KCELL) {
    const float* src = masks + ((size_t)(b * KCELL + m)) * P_;
    for (int p = t; p < P_; p += 256) { float v = src[p]; s += v; dst[p] = f2bf(v); }
  } else {
    for (int p = t; p < P_; p += 256) dst[p] = 0;
  }
  for (int off = 32; off; off >>= 1) s += __shfl_down(s, off);
  __shared__ float red[4];
  if ((t & 63) == 0) red[t >> 6] = s;
  __syncthreads();
  if (t == 0) area[b * 32 + m] = red[0] + red[1] + red[2] + red[3] + EPS_;
}

// ---------- im2col + bf16 ----------
__global__ __launch_bounds__(256) void k_im2col(const float* __restrict__ img,
                                                unsigned short* __restrict__ A) {
  int idx = blockIdx.x * 256 + threadIdx.x;   // 3,145,728 threads, 4 elems each
  int m = idx / 192, k4 = idx % 192;
  int k = k4 * 4;
  int b = m >> 10, p = m & 1023, hf = p >> 5, wf = p & 31;
  int c = k >> 8, py = (k >> 4) & 15, px = k & 15;
  const float* src = img + ((size_t)((b * 3 + c) * 512 + hf * 16 + py)) * 512 + wf * 16 + px;
  fl4 v = *(const fl4*)src;
  us4 o;
  o[0] = f2bf(v[0]); o[1] = f2bf(v[1]); o[2] = f2bf(v[2]); o[3] = f2bf(v[3]);
  *(us4*)(A + (size_t)m * KDIM + k) = o;
}

// ---------- backbone GEMM: [16384,768]x[768,2048] -> relu(+bias) -> fm bf16 ----------
// m97 structure: 128x128 tile, BK=32, 4 waves, global_load_lds w16, XCD swizzle.
__global__ __launch_bounds__(256) void k_gemm1(const unsigned short* __restrict__ A,
                                               const unsigned short* __restrict__ BT,
                                               const float* __restrict__ bias,
                                               unsigned short* __restrict__ C) {
  __shared__ unsigned short As[128 * 32];
  __shared__ unsigned short Bs[128 * 32];
  int bid = blockIdx.x;                       // 2048 blocks
  int swz = (bid & 7) * 256 + (bid >> 3);     // bijective, 2048 % 8 == 0
  int bm = swz >> 4, bn = swz & 15;
  int m0 = bm * 128, n0 = bn * 128;
  int t = threadIdx.x;
  int w = t >> 6, l = t & 63, lr = l & 15, lg = l >> 4;
  int wr = w >> 1, wc = w & 1;
  int srow = t >> 2;
  int sk = (t & 3) * 8;
  f32x4 acc[4][4] = {};
  for (int k0 = 0; k0 < KDIM; k0 += 32) {
    GLOAD16(A + (size_t)(m0 + srow) * KDIM + k0 + sk,       As + t * 8);
    GLOAD16(A + (size_t)(m0 + 64 + srow) * KDIM + k0 + sk,  As + 2048 + t * 8);
    GLOAD16(BT + (size_t)(n0 + srow) * KDIM + k0 + sk,      Bs + t * 8);
    GLOAD16(BT + (size_t)(n0 + 64 + srow) * KDIM + k0 + sk, Bs + 2048 + t * 8);
    __syncthreads();   // compiler drains vmcnt before barrier
    bf16x8 a[4], bb[4];
#pragma unroll
    for (int i = 0; i < 4; ++i) {
      a[i]  = *(const bf16x8*)(As + (wr * 64 + i * 16 + lr) * 32 + lg * 8);
      bb[i] = *(const bf16x8*)(Bs + (wc * 64 + i * 16 + lr) * 32 + lg * 8);
    }
#pragma unroll
    for (int mi = 0; mi < 4; ++mi)
#pragma unroll
      for (int ni = 0; ni < 4; ++ni)
        acc[mi][ni] = mfma16(a[mi], bb[ni], acc[mi][ni]);
    __syncthreads();
  }
#pragma unroll
  for (int mi = 0; mi < 4; ++mi)
#pragma unroll
    for (int ni = 0; ni < 4; ++ni) {
      int gcol = n0 + wc * 64 + ni * 16 + lr;
      float bv = bias[gcol];
#pragma unroll
      for (int r = 0; r < 4; ++r) {
        int grow = m0 + wr * 64 + mi * 16 + lg * 4 + r;
        float v = acc[mi][ni][r] + bv;
        v = fmaxf(v, 0.f);
        C[(size_t)grow * C_FEAT + gcol] = f2bf(v);
      }
    }
}

// ---------- masked RoI pool: per-b [32,1024]x[1024,2048] MFMA, no LDS ----------
__global__ __launch_bounds__(256) void k_pool(const unsigned short* __restrict__ mb,
                                              const unsigned short* __restrict__ fm,
                                              const float* __restrict__ area,
                                              unsigned short* __restrict__ CF) {
  int b = blockIdx.x, ct = blockIdx.y;
  int t = threadIdx.x, w = t >> 6, l = t & 63, lr = l & 15, lg = l >> 4;
  int c0 = ct * 128 + w * 32;
  const unsigned short* mbb = mb + (size_t)b * 32 * P_;
  const unsigned short* fmb = fm + (size_t)b * P_ * C_FEAT;
  f32x4 acc[2][2] = {};
  for (int k0 = 0; k0 < P_; k0 += 32) {
    int kb = k0 + lg * 8;
    bf16x8 a0 = *(const bf16x8*)(mbb + (size_t)(lr) * P_ + kb);
    bf16x8 a1 = *(const bf16x8*)(mbb + (size_t)(16 + lr) * P_ + kb);
    const unsigned short* f0 = fmb + (size_t)kb * C_FEAT + c0 + lr;
    bf16x8 b0, b1;
#pragma unroll
    for (int j = 0; j < 8; ++j) {
      b0[j] = (short)f0[(size_t)j * C_FEAT];
      b1[j] = (short)f0[(size_t)j * C_FEAT + 16];
    }
    acc[0][0] = mfma16(a0, b0, acc[0][0]);
    acc[1][0] = mfma16(a1, b0, acc[1][0]);
    acc[0][1] = mfma16(a0, b1, acc[0][1]);
    acc[1][1] = mfma16(a1, b1, acc[1][1]);
  }
#pragma unroll
  for (int mt = 0; mt < 2; ++mt)
#pragma unroll
    for (int r = 0; r < 4; ++r) {
      int m = mt * 16 + lg * 4 + r;
      if (m < KCELL) {
        float inv = 1.f / area[b * 32 + m];
#pragma unroll
        for (int nt = 0; nt < 2; ++nt) {
          int c = c0 + nt * 16 + lr;
          CF[((size_t)(b * KCELL + m)) * C_FEAT + c] = f2bf(acc[mt][nt][r] * inv);
        }
      }
    }
}

// ---------- cell class logits: cl = Wf . CF + bf*(sumM/area) ----------
__global__ __launch_bounds__(256) void k_class_logits(const unsigned short* __restrict__ CF,
                                                      const float* __restrict__ Wf,
                                                      const float* __restrict__ bfin,
                                                      const float* __restrict__ area,
                                                      float* __restrict__ cl) {
  int cell = blockIdx.x;      // 0..383
  int t = threadIdx.x;
  int c0 = t * 8;
  float cf[8];
  bf16x8 v = *(const bf16x8*)(CF + (size_t)cell * C_FEAT + c0);
#pragma unroll
  for (int j = 0; j < 8; ++j) cf[j] = bf2f((unsigned short)v[j]);
  float acc[N_CLS];
#pragma unroll
  for (int o = 0; o < N_CLS; ++o) {
    fl4 w0 = *(const fl4*)(Wf + (size_t)o * C_FEAT + c0);
    fl4 w1 = *(const fl4*)(Wf + (size_t)o * C_FEAT + c0 + 4);
    acc[o] = cf[0]*w0[0] + cf[1]*w0[1] + cf[2]*w0[2] + cf[3]*w0[3]
           + cf[4]*w1[0] + cf[5]*w1[1] + cf[6]*w1[2] + cf[7]*w1[3];
  }
#pragma unroll
  for (int o = 0; o < N_CLS; ++o)
    for (int off = 32; off; off >>= 1) acc[o] += __shfl_down(acc[o], off);
  __shared__ float red[4][N_CLS];
  if ((t & 63) == 0) {
#pragma unroll
    for (int o = 0; o < N_CLS; ++o) red[t >> 6][o] = acc[o];
  }
  __syncthreads();
  if (t < N_CLS) {
    int b = cell / KCELL, m = cell % KCELL;
    float ar = area[b * 32 + m];
    float coeff = (ar - EPS_) / ar;
    cl[(size_t)cell * N_CLS + t] =
        red[0][t] + red[1][t] + red[2][t] + red[3][t] + bfin[t] * coeff;
  }
}

// ---------- MLP layer 1: h = relu(CF @ W1^T + b1), per-wave 32x32 MFMA ----------
__global__ __launch_bounds__(256) void k_mlp1(const unsigned short* __restrict__ CF,
                                              const unsigned short* __restrict__ W1b,
                                              const float* __restrict__ b1,
                                              unsigned short* __restrict__ h) {
  int wid = blockIdx.x * 4 + (threadIdx.x >> 6);  // 0..383
  int l = threadIdx.x & 63, lr = l & 15, lg = l >> 4;
  int mt = wid >> 5, nt = wid & 31;
  int m0 = mt * 32, n0 = nt * 32;
  f32x4 acc[2][2] = {};
  for (int k0 = 0; k0 < C_FEAT; k0 += 32) {
    int kb = k0 + lg * 8;
    bf16x8 a0 = *(const bf16x8*)(CF + (size_t)(m0 + lr) * C_FEAT + kb);
    bf16x8 a1 = *(const bf16x8*)(CF + (size_t)(m0 + 16 + lr) * C_FEAT + kb);
    bf16x8 b0 = *(const bf16x8*)(W1b + (size_t)(n0 + lr) * C_FEAT + kb);
    bf16x8 b1v = *(const bf16x8*)(W1b + (size_t)(n0 + 16 + lr) * C_FEAT + kb);
    acc[0][0] = mfma16(a0, b0, acc[0][0]);
    acc[1][0] = mfma16(a1, b0, acc[1][0]);
    acc[0][1] = mfma16(a0, b1v, acc[0][1]);
    acc[1][1] = mfma16(a1, b1v, acc[1][1]);
  }
#pragma unroll
  for (int mi = 0; mi < 2; ++mi)
#pragma unroll
    for (int ni = 0; ni < 2; ++ni) {
      int col = n0 + ni * 16 + lr;
      float bv = b1[col];
#pragma unroll
      for (int r = 0; r < 4; ++r) {
        int row = m0 + mi * 16 + lg * 4 + r;
        float v = fmaxf(acc[mi][ni][r] + bv, 0.f);
        h[(size_t)row * 1024 + col] = f2bf(v);
      }
    }
}

// ---------- MLP layer 2 + per-image softmax over cells + weighted sum ----------
__global__ __launch_bounds__(512) void k_mlp2_final(const unsigned short* __restrict__ hbf,
                                                    const unsigned short* __restrict__ W2b,
                                                    const float* __restrict__ b2,
                                                    const float* __restrict__ cl,
                                                    float* __restrict__ out) {
  int b = blockIdx.x;
  int t = threadIdx.x;
  __shared__ float wl[KCELL][N_CLS + 2];
  if (t < KCELL * N_CLS) {
    int k = t / N_CLS, o = t % N_CLS;
    const unsigned short* hr = hbf + (size_t)(b * KCELL + k) * 1024;
    const unsigned short* wr = W2b + (size_t)o * 1024;
    float acc = 0.f;
    for (int c = 0; c < 1024; c += 8) {
      bf16x8 hv = *(const bf16x8*)(hr + c);
      bf16x8 wv = *(const bf16x8*)(wr + c);
#pragma unroll
      for (int j = 0; j < 8; ++j)
        acc += bf2f((unsigned short)hv[j]) * bf2f((unsigned short)wv[j]);
    }
    wl[k][o] = acc + b2[o];
  }
  __syncthreads();
  if (t < N_CLS) {
    float m = -3.4e38f;
    for (int k = 0; k < KCELL; ++k) m = fmaxf(m, wl[k][t]);
    float s = 0.f, num = 0.f;
    for (int k = 0; k < KCELL; ++k) {
      float e = expf(wl[k][t] - m);
      s += e;
      num += e * cl[(size_t)(b * KCELL + k) * N_CLS + t];
    }
    out[b * N_CLS + t] = num / s;
  }
}

// ---------- fallback (cell_counts==0): global max-pool of class maps ----------
__global__ __launch_bounds__(256) void k_fallback(const int* __restrict__ counts,
                                                  const unsigned short* __restrict__ fm,
                                                  const float* __restrict__ Wf,
                                                  const float* __restrict__ bfin,
                                                  float* __restrict__ out) {
  int b = blockIdx.x;
  if (counts[b] > 0) return;   // always taken in practice
  int t = threadIdx.x;
  float lmax[N_CLS];
#pragma unroll
  for (int o = 0; o < N_CLS; ++o) lmax[o] = -3.4e38f;
  for (int p = t; p < P_; p += 256) {
    const unsigned short* fr = fm + ((size_t)b * P_ + p) * C_FEAT;
    float acc[N_CLS];
#pragma unroll
    for (int o = 0; o < N_CLS; ++o) acc[o] = bfin[o];
    for (int c = 0; c < C_FEAT; c += 8) {
      bf16x8 v = *(const bf16x8*)(fr + c);
      float f[8];
#pragma unroll
      for (int j = 0; j < 8; ++j) f[j] = bf2f((unsigned short)v[j]);
#pragma unroll
      for (int o = 0; o < N_CLS; ++o) {
        float a = 0.f;
#pragma unroll
        for (int j = 0; j < 8; ++j) a += f[j] * Wf[(size_t)o * C_FEAT + c + j];
        acc[o] += a;
      }
    }
#pragma unroll
    for (int o = 0; o < N_CLS; ++o) lmax[o] = fmaxf(lmax[o], acc[o]);
  }
#pragma unroll
  for (int o = 0; o < N_CLS; ++o)
    for (int off = 32; off; off >>= 1) lmax[o] = fmaxf(lmax[o], __shfl_down(lmax[o], off));
  __shared__ float red[4][N_CLS];
  if ((t & 63) == 0) {
#pragma unroll
    for (int o = 0; o < N_CLS; ++o) red[t >> 6][o] = lmax[o];
  }
  __syncthreads();
  if (t < N_CLS)
    out[b * N_CLS + t] = fmaxf(fmaxf(red[0][t], red[1][t]), fmaxf(red[2][t], red[3][t]));
}

// ---------- launch ----------
extern "C" void kernel_launch(void* const* d_in, const int* in_sizes, int n_in,
                              void* d_out, int out_size, void* d_ws, size_t ws_size,
                              hipStream_t stream) {
  const float* img    = (const float*)d_in[0];
  const float* masks  = (const float*)d_in[1];
  const int*   counts = (const int*)d_in[2];
  const float* Wb     = (const float*)d_in[3];
  const float* bb     = (const float*)d_in[4];
  const float* Wf     = (const float*)d_in[5];
  const float* bfin   = (const float*)d_in[6];
  const float* W1     = (const float*)d_in[7];
  const float* b1     = (const float*)d_in[8];
  const float* W2     = (const float*)d_in[9];
  const float* b2     = (const float*)d_in[10];
  float* out = (float*)d_out;

  char* ws = (char*)d_ws;
  unsigned short* Abf  = (unsigned short*)(ws + OFF_A);
  unsigned short* Wbb  = (unsigned short*)(ws + OFF_WB);
  unsigned short* W1b  = (unsigned short*)(ws + OFF_W1);
  unsigned short* W2b  = (unsigned short*)(ws + OFF_W2);
  unsigned short* fmb  = (unsigned short*)(ws + OFF_FM);
  unsigned short* mbb  = (unsigned short*)(ws + OFF_MB);
  float*          area = (float*)(ws + OFF_AREA);
  unsigned short* CF   = (unsigned short*)(ws + OFF_CF);
  float*          cl   = (float*)(ws + OFF_CL);
  unsigned short* hb   = (unsigned short*)(ws + OFF_H);

  // weight conversions
  k_f2bf<<<(2048 * 768 / 4 + 255) / 256, 256, 0, stream>>>(Wb, Wbb, 2048 * 768 / 4);
  k_f2bf<<<(1024 * 2048 / 4 + 255) / 256, 256, 0, stream>>>(W1, W1b, 1024 * 2048 / 4);
  k_f2bf<<<(18 * 1024 / 4 + 255) / 256, 256, 0, stream>>>(W2, W2b, 18 * 1024 / 4);
  // masks prep + area
  k_prep_masks<<<B_ * 32, 256, 0, stream>>>(masks, mbb, area);
  // im2col
  k_im2col<<<(M_GEMM1 * KDIM / 4) / 256, 256, 0, stream>>>(img, Abf);
  // backbone GEMM -> fm
  k_gemm1<<<(M_GEMM1 / 128) * (C_FEAT / 128), 256, 0, stream>>>(Abf, Wbb, bb, fmb);
  // masked RoI pooling -> CF
  k_pool<<<dim3(B_, C_FEAT / 128), 256, 0, stream>>>(mbb, fmb, area, CF);
  // class logits
  k_class_logits<<<B_ * KCELL, 256, 0, stream>>>(CF, Wf, bfin, area, cl);
  // MLP
  k_mlp1<<<(384 / 32) * (1024 / 32) / 4, 256, 0, stream>>>(CF, W1b, b1, hb);
  k_mlp2_final<<<B_, 512, 0, stream>>>(hb, W2b, b2, cl, out);
  // zero-count fallback (early-exits when counts>0)
  k_fallback<<<B_, 256, 0, stream>>>(counts, fmb, Wf, bfin, out);
}

// Round 4
// 278.409 us; speedup vs baseline: 1.0278x; 1.0278x over previous
//
#include <hip/hip_runtime.h>

// ---------- problem constants ----------
#define B_      16
#define C_IN    3
#define IMG     512
#define PATCH   16
#define C_FEAT  2048
#define N_CLS   18
#define KCELL   24
#define HF      32
#define P_      (HF*HF)        // 1024
#define KDIM    (C_IN*PATCH*PATCH) // 768
#define M_GEMM1 (B_*P_)        // 16384
#define EPS_    1e-6f

typedef __attribute__((ext_vector_type(8))) short bf16x8;
typedef __attribute__((ext_vector_type(4))) float f32x4;
typedef __attribute__((ext_vector_type(4))) unsigned short us4;
typedef __attribute__((ext_vector_type(8))) unsigned short us8;
typedef __attribute__((ext_vector_type(4))) float fl4;

#define DEVFN static __device__ __forceinline__

DEVFN unsigned short f2bf(float f) {  // RNE f32->bf16
  union { float f; unsigned u; } x; x.f = f;
  unsigned r = (x.u + 0x7fffu + ((x.u >> 16) & 1u)) >> 16;
  return (unsigned short)r;
}
DEVFN float bf2f(unsigned short u) {
  union { unsigned u; float f; } x; x.u = ((unsigned)u) << 16;
  return x.f;
}
DEVFN f32x4 mfma16(bf16x8 a, bf16x8 b, f32x4 c) {
  return __builtin_amdgcn_mfma_f32_16x16x32_bf16(a, b, c, 0, 0, 0);
}
#define GLOAD16(gp, lp) __builtin_amdgcn_global_load_lds( \
    (const __attribute__((address_space(1))) unsigned int*)(gp), \
    (__attribute__((address_space(3))) unsigned int*)(lp), 16, 0, 0)

// ---------- ws layout (bytes) ----------
#define OFF_A     0u            // A_bf16 [16384][768]        25,165,824
#define OFF_WB    25165824u     // Wb_bf16 [2048][768]         3,145,728
#define OFF_W1    28311552u     // W1_bf16 [1024][2048]        4,194,304
#define OFF_W2    32505856u     // W2_bf16 [18][1024]             36,864
#define OFF_FM    32542720u     // fmT_bf16 [16][2048][1024]  67,108,864  (channel-major!)
#define OFF_MB    99651584u     // masks_bf16 [16][32][1024]   1,048,576
#define OFF_AREA  100700160u    // area [16*32] f32                2,048
#define OFF_CF    100702208u    // CF_bf16 [384][2048]         1,572,864
#define OFF_CL    102275072u    // cl f32 [384][18]               27,648
#define OFF_H     102302720u    // h_bf16 [384][1024]            786,432
#define WS_NEED   103089152u

// ---------- merged prep: masks (+area) and 3 weight f32->bf16 converts ----------
// blocks [0,512): masks | [512,1280): Wb | [1280,2304): W1 | [2304,2313): W2
__global__ __launch_bounds__(256) void k_prep(const float* __restrict__ masks,
                                              const float* __restrict__ Wb,
                                              const float* __restrict__ W1,
                                              const float* __restrict__ W2,
                                              unsigned short* __restrict__ mb,
                                              float* __restrict__ area,
                                              unsigned short* __restrict__ Wbb,
                                              unsigned short* __restrict__ W1b,
                                              unsigned short* __restrict__ W2b) {
  int blk = blockIdx.x;
  int t = threadIdx.x;
  if (blk < 512) {
    int b = blk >> 5, m = blk & 31;
    unsigned short* dst = mb + ((size_t)(b * 32 + m)) * P_;
    float s = 0.f;
    if (m < KCELL) {
      const float* src = masks + ((size_t)(b * KCELL + m)) * P_;
      for (int p = t; p < P_; p += 256) { float v = src[p]; s += v; dst[p] = f2bf(v); }
    } else {
      for (int p = t; p < P_; p += 256) dst[p] = 0;
    }
    for (int off = 32; off; off >>= 1) s += __shfl_down(s, off);
    __shared__ float red[4];
    if ((t & 63) == 0) red[t >> 6] = s;
    __syncthreads();
    if (t == 0) area[b * 32 + m] = red[0] + red[1] + red[2] + red[3] + EPS_;
    return;
  }
  const float* src; unsigned short* dst; int local, n;
  if (blk < 1280)      { src = Wb; dst = Wbb; local = blk - 512;  n = C_FEAT * KDIM; }
  else if (blk < 2304) { src = W1; dst = W1b; local = blk - 1280; n = 1024 * C_FEAT; }
  else                 { src = W2; dst = W2b; local = blk - 2304; n = N_CLS * 1024; }
  int i = (local * 256 + t) * 8;
  if (i + 8 <= n) {
    fl4 v0 = *(const fl4*)(src + i);
    fl4 v1 = *(const fl4*)(src + i + 4);
    us8 o;
    o[0] = f2bf(v0[0]); o[1] = f2bf(v0[1]); o[2] = f2bf(v0[2]); o[3] = f2bf(v0[3]);
    o[4] = f2bf(v1[0]); o[5] = f2bf(v1[1]); o[6] = f2bf(v1[2]); o[7] = f2bf(v1[3]);
    *(us8*)(dst + i) = o;
  }
}

// ---------- im2col + bf16 (32B read / 16B write per lane) ----------
__global__ __launch_bounds__(256) void k_im2col(const float* __restrict__ img,
                                                unsigned short* __restrict__ A) {
  int idx = blockIdx.x * 256 + threadIdx.x;   // 1,572,864 threads, 8 elems each
  int m = idx / 96, k8 = idx % 96;
  int k = k8 * 8;
  int b = m >> 10, p = m & 1023, hf = p >> 5, wf = p & 31;
  int c = k >> 8, py = (k >> 4) & 15, px = k & 15;
  const float* src = img + ((size_t)((b * 3 + c) * 512 + hf * 16 + py)) * 512 + wf * 16 + px;
  fl4 v0 = *(const fl4*)src;
  fl4 v1 = *(const fl4*)(src + 4);
  us8 o;
  o[0] = f2bf(v0[0]); o[1] = f2bf(v0[1]); o[2] = f2bf(v0[2]); o[3] = f2bf(v0[3]);
  o[4] = f2bf(v1[0]); o[5] = f2bf(v1[1]); o[6] = f2bf(v1[2]); o[7] = f2bf(v1[3]);
  *(us8*)(A + (size_t)m * KDIM + k) = o;
}

// ---------- backbone GEMM: [16384,768]x[768,2048] -> relu(+bias) -> fmT bf16 ----------
// m97 structure: 128x128 tile, BK=32, 4 waves, global_load_lds w16, XCD swizzle.
// Output written CHANNEL-MAJOR: fmT[b][c][p], p = m & 1023.
__global__ __launch_bounds__(256) void k_gemm1(const unsigned short* __restrict__ A,
                                               const unsigned short* __restrict__ BT,
                                               const float* __restrict__ bias,
                                               unsigned short* __restrict__ CT) {
  __shared__ unsigned short As[128 * 32];
  __shared__ unsigned short Bs[128 * 32];
  int bid = blockIdx.x;                       // 2048 blocks
  int swz = (bid & 7) * 256 + (bid >> 3);     // bijective, 2048 % 8 == 0
  int bm = swz >> 4, bn = swz & 15;
  int m0 = bm * 128, n0 = bn * 128;
  int t = threadIdx.x;
  int w = t >> 6, l = t & 63, lr = l & 15, lg = l >> 4;
  int wr = w >> 1, wc = w & 1;
  int srow = t >> 2;
  int sk = (t & 3) * 8;
  f32x4 acc[4][4] = {};
  for (int k0 = 0; k0 < KDIM; k0 += 32) {
    GLOAD16(A + (size_t)(m0 + srow) * KDIM + k0 + sk,       As + t * 8);
    GLOAD16(A + (size_t)(m0 + 64 + srow) * KDIM + k0 + sk,  As + 2048 + t * 8);
    GLOAD16(BT + (size_t)(n0 + srow) * KDIM + k0 + sk,      Bs + t * 8);
    GLOAD16(BT + (size_t)(n0 + 64 + srow) * KDIM + k0 + sk, Bs + 2048 + t * 8);
    __syncthreads();   // compiler drains vmcnt before barrier
    bf16x8 a[4], bb[4];
#pragma unroll
    for (int i = 0; i < 4; ++i) {
      a[i]  = *(const bf16x8*)(As + (wr * 64 + i * 16 + lr) * 32 + lg * 8);
      bb[i] = *(const bf16x8*)(Bs + (wc * 64 + i * 16 + lr) * 32 + lg * 8);
    }
#pragma unroll
    for (int mi = 0; mi < 4; ++mi)
#pragma unroll
      for (int ni = 0; ni < 4; ++ni)
        acc[mi][ni] = mfma16(a[mi], bb[ni], acc[mi][ni]);
    __syncthreads();
  }
  // epilogue: relu(acc+bias) -> fmT[b][c][p], packed 4-p (8B) stores
  int b = m0 >> 10;
  int pbase0 = (m0 & 1023) + wr * 64 + lg * 4;
#pragma unroll
  for (int ni = 0; ni < 4; ++ni) {
    int gcol = n0 + wc * 64 + ni * 16 + lr;
    float bv = bias[gcol];
    unsigned short* crow = CT + ((size_t)(b * C_FEAT + gcol)) * P_;
#pragma unroll
    for (int mi = 0; mi < 4; ++mi) {
      us4 o;
#pragma unroll
      for (int r = 0; r < 4; ++r)
        o[r] = f2bf(fmaxf(acc[mi][ni][r] + bv, 0.f));
      *(us4*)(crow + pbase0 + mi * 16) = o;
    }
  }
}

// ---------- masked RoI pool on fmT: per-(b,128ch) [32,1024]x[1024,32] MFMA ----------
// Both operands k(=p)-contiguous bf16x8 loads now.
__global__ __launch_bounds__(256) void k_pool(const unsigned short* __restrict__ mb,
                                              const unsigned short* __restrict__ fmT,
                                              const float* __restrict__ area,
                                              unsigned short* __restrict__ CF) {
  int b = blockIdx.x, ct = blockIdx.y;
  int t = threadIdx.x, w = t >> 6, l = t & 63, lr = l & 15, lg = l >> 4;
  int c0 = ct * 128 + w * 32;
  const unsigned short* mbb = mb + (size_t)b * 32 * P_;
  const unsigned short* fb = fmT + (size_t)b * C_FEAT * P_;
  f32x4 acc[2][2] = {};
  for (int k0 = 0; k0 < P_; k0 += 32) {
    int kb = k0 + lg * 8;
    bf16x8 a0 = *(const bf16x8*)(mbb + (size_t)lr * P_ + kb);
    bf16x8 a1 = *(const bf16x8*)(mbb + (size_t)(16 + lr) * P_ + kb);
    bf16x8 b0 = *(const bf16x8*)(fb + (size_t)(c0 + lr) * P_ + kb);
    bf16x8 b1 = *(const bf16x8*)(fb + (size_t)(c0 + 16 + lr) * P_ + kb);
    acc[0][0] = mfma16(a0, b0, acc[0][0]);
    acc[1][0] = mfma16(a1, b0, acc[1][0]);
    acc[0][1] = mfma16(a0, b1, acc[0][1]);
    acc[1][1] = mfma16(a1, b1, acc[1][1]);
  }
#pragma unroll
  for (int mt = 0; mt < 2; ++mt)
#pragma unroll
    for (int r = 0; r < 4; ++r) {
      int m = mt * 16 + lg * 4 + r;
      if (m < KCELL) {
        float inv = 1.f / area[b * 32 + m];
#pragma unroll
        for (int nt = 0; nt < 2; ++nt) {
          int c = c0 + nt * 16 + lr;
          CF[((size_t)(b * KCELL + m)) * C_FEAT + c] = f2bf(acc[mt][nt][r] * inv);
        }
      }
    }
}

// ---------- cell class logits: cl = Wf . CF + bf*(sumM/area) ----------
__global__ __launch_bounds__(256) void k_class_logits(const unsigned short* __restrict__ CF,
                                                      const float* __restrict__ Wf,
                                                      const float* __restrict__ bfin,
                                                      const float* __restrict__ area,
                                                      float* __restrict__ cl) {
  int cell = blockIdx.x;      // 0..383
  int t = threadIdx.x;
  int c0 = t * 8;
  float cf[8];
  bf16x8 v = *(const bf16x8*)(CF + (size_t)cell * C_FEAT + c0);
#pragma unroll
  for (int j = 0; j < 8; ++j) cf[j] = bf2f((unsigned short)v[j]);
  float acc[N_CLS];
#pragma unroll
  for (int o = 0; o < N_CLS; ++o) {
    fl4 w0 = *(const fl4*)(Wf + (size_t)o * C_FEAT + c0);
    fl4 w1 = *(const fl4*)(Wf + (size_t)o * C_FEAT + c0 + 4);
    acc[o] = cf[0]*w0[0] + cf[1]*w0[1] + cf[2]*w0[2] + cf[3]*w0[3]
           + cf[4]*w1[0] + cf[5]*w1[1] + cf[6]*w1[2] + cf[7]*w1[3];
  }
#pragma unroll
  for (int o = 0; o < N_CLS; ++o)
    for (int off = 32; off; off >>= 1) acc[o] += __shfl_down(acc[o], off);
  __shared__ float red[4][N_CLS];
  if ((t & 63) == 0) {
#pragma unroll
    for (int o = 0; o < N_CLS; ++o) red[t >> 6][o] = acc[o];
  }
  __syncthreads();
  if (t < N_CLS) {
    int b = cell / KCELL, m = cell % KCELL;
    float ar = area[b * 32 + m];
    float coeff = (ar - EPS_) / ar;
    cl[(size_t)cell * N_CLS + t] =
        red[0][t] + red[1][t] + red[2][t] + red[3][t] + bfin[t] * coeff;
  }
}

// ---------- MLP layer 1: h = relu(CF @ W1^T + b1), 16x16 wave tiles ----------
__global__ __launch_bounds__(256) void k_mlp1(const unsigned short* __restrict__ CF,
                                              const unsigned short* __restrict__ W1b,
                                              const float* __restrict__ b1,
                                              unsigned short* __restrict__ h) {
  int wid = blockIdx.x * 4 + (threadIdx.x >> 6);  // 0..1535
  int l = threadIdx.x & 63, lr = l & 15, lg = l >> 4;
  int mt = wid >> 6, nt = wid & 63;               // 24 x 64 tiles
  int m0 = mt * 16, n0 = nt * 16;
  f32x4 acc = {};
  for (int k0 = 0; k0 < C_FEAT; k0 += 32) {
    int kb = k0 + lg * 8;
    bf16x8 a = *(const bf16x8*)(CF + (size_t)(m0 + lr) * C_FEAT + kb);
    bf16x8 b = *(const bf16x8*)(W1b + (size_t)(n0 + lr) * C_FEAT + kb);
    acc = mfma16(a, b, acc);
  }
  int col = n0 + lr;
  float bv = b1[col];
#pragma unroll
  for (int r = 0; r < 4; ++r) {
    int row = m0 + lg * 4 + r;
    h[(size_t)row * 1024 + col] = f2bf(fmaxf(acc[r] + bv, 0.f));
  }
}

// ---------- MLP layer 2 + per-image softmax over cells + weighted sum ----------
__global__ __launch_bounds__(512) void k_mlp2_final(const unsigned short* __restrict__ hbf,
                                                    const unsigned short* __restrict__ W2b,
                                                    const float* __restrict__ b2,
                                                    const float* __restrict__ cl,
                                                    float* __restrict__ out) {
  int b = blockIdx.x;
  int t = threadIdx.x;
  __shared__ float wl[KCELL][N_CLS + 2];
  if (t < KCELL * N_CLS) {
    int k = t / N_CLS, o = t % N_CLS;
    const unsigned short* hr = hbf + (size_t)(b * KCELL + k) * 1024;
    const unsigned short* wr = W2b + (size_t)o * 1024;
    float acc = 0.f;
    for (int c = 0; c < 1024; c += 8) {
      bf16x8 hv = *(const bf16x8*)(hr + c);
      bf16x8 wv = *(const bf16x8*)(wr + c);
#pragma unroll
      for (int j = 0; j < 8; ++j)
        acc += bf2f((unsigned short)hv[j]) * bf2f((unsigned short)wv[j]);
    }
    wl[k][o] = acc + b2[o];
  }
  __syncthreads();
  if (t < N_CLS) {
    float m = -3.4e38f;
    for (int k = 0; k < KCELL; ++k) m = fmaxf(m, wl[k][t]);
    float s = 0.f, num = 0.f;
    for (int k = 0; k < KCELL; ++k) {
      float e = expf(wl[k][t] - m);
      s += e;
      num += e * cl[(size_t)(b * KCELL + k) * N_CLS + t];
    }
    out[b * N_CLS + t] = num / s;
  }
}

// ---------- fallback (cell_counts==0): global max-pool of class maps (cold path) ----------
__global__ __launch_bounds__(256) void k_fallback(const int* __restrict__ counts,
                                                  const unsigned short* __restrict__ fmT,
                                                  const float* __restrict__ Wf,
                                                  const float* __restrict__ bfin,
                                                  float* __restrict__ out) {
  int b = blockIdx.x;
  if (counts[b] > 0) return;   // always taken for these inputs
  int t = threadIdx.x;
  const unsigned short* fb = fmT + (size_t)b * C_FEAT * P_;
  float lmax[N_CLS];
#pragma unroll
  for (int o = 0; o < N_CLS; ++o) lmax[o] = -3.4e38f;
  for (int p = t; p < P_; p += 256) {
    float acc[N_CLS];
#pragma unroll
    for (int o = 0; o < N_CLS; ++o) acc[o] = bfin[o];
    for (int c = 0; c < C_FEAT; ++c) {
      float f = bf2f(fb[(size_t)c * P_ + p]);
#pragma unroll
      for (int o = 0; o < N_CLS; ++o) acc[o] += f * Wf[(size_t)o * C_FEAT + c];
    }
#pragma unroll
    for (int o = 0; o < N_CLS; ++o) lmax[o] = fmaxf(lmax[o], acc[o]);
  }
#pragma unroll
  for (int o = 0; o < N_CLS; ++o)
    for (int off = 32; off; off >>= 1) lmax[o] = fmaxf(lmax[o], __shfl_down(lmax[o], off));
  __shared__ float red[4][N_CLS];
  if ((t & 63) == 0) {
#pragma unroll
    for (int o = 0; o < N_CLS; ++o) red[t >> 6][o] = lmax[o];
  }
  __syncthreads();
  if (t < N_CLS)
    out[b * N_CLS + t] = fmaxf(fmaxf(red[0][t], red[1][t]), fmaxf(red[2][t], red[3][t]));
}

// ---------- launch ----------
extern "C" void kernel_launch(void* const* d_in, const int* in_sizes, int n_in,
                              void* d_out, int out_size, void* d_ws, size_t ws_size,
                              hipStream_t stream) {
  const float* img    = (const float*)d_in[0];
  const float* masks  = (const float*)d_in[1];
  const int*   counts = (const int*)d_in[2];
  const float* Wb     = (const float*)d_in[3];
  const float* bb     = (const float*)d_in[4];
  const float* Wf     = (const float*)d_in[5];
  const float* bfin   = (const float*)d_in[6];
  const float* W1     = (const float*)d_in[7];
  const float* b1     = (const float*)d_in[8];
  const float* W2     = (const float*)d_in[9];
  const float* b2     = (const float*)d_in[10];
  float* out = (float*)d_out;

  char* ws = (char*)d_ws;
  unsigned short* Abf  = (unsigned short*)(ws + OFF_A);
  unsigned short* Wbb  = (unsigned short*)(ws + OFF_WB);
  unsigned short* W1b  = (unsigned short*)(ws + OFF_W1);
  unsigned short* W2b  = (unsigned short*)(ws + OFF_W2);
  unsigned short* fmT  = (unsigned short*)(ws + OFF_FM);
  unsigned short* mbb  = (unsigned short*)(ws + OFF_MB);
  float*          area = (float*)(ws + OFF_AREA);
  unsigned short* CF   = (unsigned short*)(ws + OFF_CF);
  float*          cl   = (float*)(ws + OFF_CL);
  unsigned short* hb   = (unsigned short*)(ws + OFF_H);

  // merged prep: masks+area, Wb/W1/W2 -> bf16
  k_prep<<<2313, 256, 0, stream>>>(masks, Wb, W1, W2, mbb, area, Wbb, W1b, W2b);
  // im2col
  k_im2col<<<(M_GEMM1 * KDIM / 8) / 256, 256, 0, stream>>>(img, Abf);
  // backbone GEMM -> fmT (channel-major)
  k_gemm1<<<(M_GEMM1 / 128) * (C_FEAT / 128), 256, 0, stream>>>(Abf, Wbb, bb, fmT);
  // masked RoI pooling -> CF
  k_pool<<<dim3(B_, C_FEAT / 128), 256, 0, stream>>>(mbb, fmT, area, CF);
  // class logits
  k_class_logits<<<B_ * KCELL, 256, 0, stream>>>(CF, Wf, bfin, area, cl);
  // MLP
  k_mlp1<<<(24 * 64) / 4, 256, 0, stream>>>(CF, W1b, b1, hb);
  k_mlp2_final<<<B_, 512, 0, stream>>>(hb, W2b, b2, cl, out);
  // zero-count fallback (early-exits when counts>0)
  k_fallback<<<B_, 256, 0, stream>>>(counts, fmT, Wf, bfin, out);
}